// Round 3
// baseline (396.960 us; speedup 1.0000x reference)
//
#include <hip/hip_runtime.h>

#define BB 32
#define CC 64
#define HH 56
#define WW 56
#define HW 3136
#define TW 64
#define TR 12

// ---------------- merged prep: (a) qproj blocks [0,800)  (b) WK blocks [800,928) ----------------
__global__ __launch_bounds__(256) void prep_q_k(const float* __restrict__ x,
                                                const float* __restrict__ wk,
                                                const float* __restrict__ wks,
                                                const float* __restrict__ wkb,
                                                const float* __restrict__ wp_w,
                                                const float* __restrict__ wq_w,
                                                const float* __restrict__ wq_s,
                                                const float* __restrict__ wq_bb,
                                                float* __restrict__ WK,
                                                float* __restrict__ qws) {
    __shared__ float p_s[32 * 49];
    __shared__ float kg_s[8 * 49];
    __shared__ float wqT_s[32 * 32];
    __shared__ float qbn_s[64];
    const int tid = threadIdx.x;
    const int bx = blockIdx.x;

    if (bx < 800) {
        // ---------- qproj role: q_ws[b,32,HW] = bn(wq . x[:,0:32]) * SCALE ----------
        for (int idx = tid; idx < 1024; idx += 256) {
            const int o = idx & 31, i = idx >> 5;
            wqT_s[i * 32 + o] = wq_w[o * 32 + i];
        }
        if (tid < 32) { qbn_s[tid] = wq_s[tid]; qbn_s[32 + tid] = wq_bb[tid]; }
        __syncthreads();
        const int b = bx / 25, t = bx % 25;
        const int p4 = t * 32 + (tid & 31);
        if (p4 >= 784) return;
        const int oo = (tid >> 5) * 4;
        const float* xp = x + (long)b * CC * HW + p4 * 4;
        float4 acc[4];
        #pragma unroll
        for (int o = 0; o < 4; ++o) acc[o] = make_float4(0.f, 0.f, 0.f, 0.f);
        for (int ii = 0; ii < 32; ii += 8) {
            float4 mv[8];
            #pragma unroll
            for (int u = 0; u < 8; ++u)
                mv[u] = *reinterpret_cast<const float4*>(xp + (long)(ii + u) * HW);
            #pragma unroll
            for (int u = 0; u < 8; ++u) {
                const float* wr = wqT_s + (ii + u) * 32 + oo;
                #pragma unroll
                for (int o = 0; o < 4; ++o) {
                    const float wv = wr[o];
                    acc[o].x = fmaf(wv, mv[u].x, acc[o].x);
                    acc[o].y = fmaf(wv, mv[u].y, acc[o].y);
                    acc[o].z = fmaf(wv, mv[u].z, acc[o].z);
                    acc[o].w = fmaf(wv, mv[u].w, acc[o].w);
                }
            }
        }
        float* qp = qws + (long)b * 32 * HW + p4 * 4;
        #pragma unroll
        for (int o = 0; o < 4; ++o) {
            const float sc = qbn_s[oo + o] * 0.25f;       // fold SCALE into bn
            const float bc = qbn_s[32 + oo + o] * 0.25f;
            float4 r;
            r.x = fmaf(acc[o].x, sc, bc);
            r.y = fmaf(acc[o].y, sc, bc);
            r.z = fmaf(acc[o].z, sc, bc);
            r.w = fmaf(acc[o].w, sc, bc);
            *reinterpret_cast<float4*>(qp + (long)(oo + o) * HW) = r;
        }
        return;
    }

    // ---------- prep (WK) role ----------
    const int id = bx - 800;
    const int b = id >> 2;
    const int g = id & 3;
    for (int idx = tid; idx < 1568; idx += 256) {
        const int i = idx / 49, l = idx % 49;
        const int py = l / 7, px = l % 7;
        const float4* xp4 = reinterpret_cast<const float4*>(
            x + ((long)(b * CC + 32 + i)) * HW + py * 8 * WW + px * 8);
        float4 sA = make_float4(0.f, 0.f, 0.f, 0.f);
        float4 sB = make_float4(0.f, 0.f, 0.f, 0.f);
        #pragma unroll
        for (int y = 0; y < 8; ++y) {
            const float4 a = xp4[y * 14];
            const float4 c = xp4[y * 14 + 1];
            sA.x += a.x; sA.y += a.y; sA.z += a.z; sA.w += a.w;
            sB.x += c.x; sB.y += c.y; sB.z += c.z; sB.w += c.w;
        }
        p_s[idx] = (sA.x + sA.y + sA.z + sA.w + sB.x + sB.y + sB.z + sB.w) * (1.f / 64.f);
    }
    __syncthreads();
    for (int idx = tid; idx < 392; idx += 256) {
        const int o8 = idx / 49, l = idx % 49;
        const int o = g * 8 + o8;
        float acc = 0.f;
        #pragma unroll
        for (int i = 0; i < 32; ++i) acc = fmaf(wk[o * 32 + i], p_s[i * 49 + l], acc);
        kg_s[idx] = acc * wks[o] + wkb[o];
    }
    __syncthreads();
    for (int idx = tid; idx < 640; idx += 256) {
        const int c = idx / 80, slot = idx % 80;
        float acc = 0.f;
        int m = -1;
        if (slot < 28) { if (slot < 25) m = slot; }
        else           { if (slot < 77) m = 25 + (slot - 28); }
        if (m >= 0) {
            const float* kp = kg_s + c * 49;
            #pragma unroll
            for (int l = 0; l < 49; ++l) acc = fmaf(wp_w[m * 49 + l], kp[l], acc);
        }
        const long base = (long)id * 640;
        if (slot < 28) WK[base + c * 28 + slot] = acc;
        else           WK[base + 224 + c * 52 + (slot - 28)] = acc;
    }
}

// ---------------- fused attention + dyn_mix + lepe; one block = one (b,g,half) ----------------
// Wave-uniform operands (WK, wp_b, lepe weights, bn scalars) are read straight from global
// memory with block-uniform addresses -> compiler emits s_load into SGPRs (SMEM pipe),
// freeing the per-CU LDS pipe for the per-lane tile/rpb reads. LDS = tile + rpb only.
__global__ __launch_bounds__(256, 5) void attnmix_k(const float* __restrict__ x,
                                                    const float* __restrict__ WK,
                                                    const float* __restrict__ qws,
                                                    const float* __restrict__ wp_b,
                                                    const float* __restrict__ rpb1,
                                                    const float* __restrict__ rpb2,
                                                    const float* __restrict__ lw,
                                                    const float* __restrict__ lb,
                                                    const float* __restrict__ ls,
                                                    const float* __restrict__ lbb,
                                                    float* __restrict__ mix,
                                                    float* __restrict__ out) {
    __shared__ float tile[8 * TR * TW];            // 24 KB
    __shared__ float rpb_s[169];
    const int tid = threadIdx.x;
    const int yb = blockIdx.y;
    const int half = yb & 1, bg = yb >> 1;
    const int g = bg & 3, b = bg >> 2;
    const int ch0 = (half ? 32 : 0) + g * 8;       // x/out channel base for this block

    // uniform-address bases (scalar loads at use sites)
    const float* wkp = WK + (long)bg * 640 + (half ? 224 : 0);
    const float* wpb = wp_b + (half ? 25 : 0);
    const float* lwp = lw + ch0 * 49;

    {   // rpb is indexed per-lane -> stage in LDS
        const int nr = half ? 169 : 81;
        const float* rp = half ? (rpb2 + g * 169) : (rpb1 + g * 81);
        if (tid < nr) rpb_s[tid] = rp[tid];
    }

    const int N0 = blockIdx.x << 8;
    const int ph0 = N0 / WW;                       // block-uniform
    const int r0 = ph0 - 3;

    const int n = N0 + tid;
    const bool valid = n < HW;
    const int nc = valid ? n : HW - 1;
    const int ph = nc / WW, pw = nc % WW;
    const int yr = HH - 1 - ph, xr = WW - 1 - pw;
    const int lrow = ph - r0;                      // in [3, 8]
    const int tb0 = (lrow - 3) * TW + pw;          // tile offset of tap (0,0)

    // q8 loads issued before staging so they overlap the tile fill
    const float* qp = qws + ((long)b * 32 + g * 8) * HW + nc;
    float q8[8];
    #pragma unroll
    for (int c = 0; c < 8; ++c) q8[c] = qp[c * HW];

    // ---- stage the 8 value channels of this half (zero-padded halo) ----
    {
        const float* xc = x + ((long)b * CC + ch0) * HW;
        #pragma unroll
        for (int ch = 0; ch < 8; ++ch)
            for (int k = tid; k < TR * TW; k += 256) {
                const int row = k >> 6, lxx = k & 63;
                const int gy = r0 + row, gx = lxx - 3;
                float v = 0.f;
                if ((unsigned)gy < HH && (unsigned)gx < WW) v = xc[ch * HW + gy * WW + gx];
                tile[ch * (TR * TW) + k] = v;
            }
    }
    __syncthreads();

    float* mp = mix + ((long)b * CC + ch0) * HW + nc;
    float* op = out + ((long)b * CC + ch0) * HW + nc;

    if (half == 0) {
        // ======== 25-weight softmax, 5x5 gather + lepe 7x7 ========
        float w1[25];
        #pragma unroll
        for (int m = 0; m < 25; ++m) w1[m] = wpb[m];
        #pragma unroll
        for (int c = 0; c < 8; ++c) {
            const float qv = q8[c];
            #pragma unroll
            for (int m = 0; m < 25; ++m) w1[m] = fmaf(qv, wkp[c * 28 + m], w1[m]);
        }
        const int rh5 = yr < 2 ? yr : (yr > 53 ? yr - 51 : 2);
        const int rw5 = xr < 2 ? xr : (xr > 53 ? xr - 51 : 2);
        #pragma unroll
        for (int i = 0; i < 5; ++i)
            #pragma unroll
            for (int j = 0; j < 5; ++j)
                w1[i * 5 + j] += rpb_s[(rh5 + i) * 9 + (rw5 + j)];
        float mx = -1e30f;
        #pragma unroll
        for (int m = 0; m < 25; ++m) mx = fmaxf(mx, w1[m]);
        float sm = 0.f;
        #pragma unroll
        for (int m = 0; m < 25; ++m) { w1[m] = __expf(w1[m] - mx); sm += w1[m]; }
        const float r = 1.f / sm;
        #pragma unroll
        for (int m = 0; m < 25; ++m) w1[m] *= r;

        #pragma unroll
        for (int ch = 0; ch < 8; ++ch) {
            const float* t = tile + ch * (TR * TW) + tb0;
            const float* lwc = lwp + ch * 49;      // uniform -> s_load
            float a = 0.f, la = 0.f;
            #pragma unroll
            for (int i = 0; i < 7; ++i)
                #pragma unroll
                for (int j = 0; j < 7; ++j) {
                    const float v = t[i * TW + j];
                    la = fmaf(lwc[i * 7 + j], v, la);
                    if (i >= 1 && i <= 5 && j >= 1 && j <= 5)
                        a = fmaf(w1[(i - 1) * 5 + (j - 1)], v, a);
                }
            if (valid) {
                mp[ch * HW] = a;
                op[ch * HW] = (la + lb[ch0 + ch]) * ls[ch0 + ch] + lbb[ch0 + ch];
            }
        }
    } else {
        // ======== 49-weight softmax, 7x7 gather + lepe 7x7 ========
        float w2[49];
        #pragma unroll
        for (int m = 0; m < 49; ++m) w2[m] = wpb[m];
        #pragma unroll
        for (int c = 0; c < 8; ++c) {
            const float qv = q8[c];
            #pragma unroll
            for (int m = 0; m < 49; ++m) w2[m] = fmaf(qv, wkp[c * 52 + m], w2[m]);
        }
        const int rh7 = yr < 3 ? yr : (yr > 52 ? yr - 49 : 3);
        const int rw7 = xr < 3 ? xr : (xr > 52 ? xr - 49 : 3);
        #pragma unroll
        for (int i = 0; i < 7; ++i)
            #pragma unroll
            for (int j = 0; j < 7; ++j)
                w2[i * 7 + j] += rpb_s[(rh7 + i) * 13 + (rw7 + j)];
        float mx = -1e30f;
        #pragma unroll
        for (int m = 0; m < 49; ++m) mx = fmaxf(mx, w2[m]);
        float sm = 0.f;
        #pragma unroll
        for (int m = 0; m < 49; ++m) { w2[m] = __expf(w2[m] - mx); sm += w2[m]; }
        const float r = 1.f / sm;
        #pragma unroll
        for (int m = 0; m < 49; ++m) w2[m] *= r;

        #pragma unroll
        for (int ch = 0; ch < 8; ++ch) {
            const float* t = tile + ch * (TR * TW) + tb0;
            const float* lwc = lwp + ch * 49;      // uniform -> s_load
            float a = 0.f, la = 0.f;
            #pragma unroll
            for (int i = 0; i < 7; ++i)
                #pragma unroll
                for (int j = 0; j < 7; ++j) {
                    const float v = t[i * TW + j];
                    la = fmaf(lwc[i * 7 + j], v, la);
                    a  = fmaf(w2[i * 7 + j], v, a);
                }
            if (valid) {
                mp[ch * HW] = a;
                op[ch * HW] = (la + lb[ch0 + ch]) * ls[ch0 + ch] + lbb[ch0 + ch];
            }
        }
    }
}

// ---------------- final: 64x64 channel matmul + bn + lepe add ----------------
__global__ __launch_bounds__(256) void final_k(const float* __restrict__ mix,
                                               const float* __restrict__ dy_w,
                                               const float* __restrict__ s,
                                               const float* __restrict__ bb,
                                               float* __restrict__ out) {
    __shared__ float w_s[64 * 64];      // transposed: w_s[i*64+o] = dy_w[o*64+i]
    const int tid = threadIdx.x;
    const int b = blockIdx.y;
    for (int i = tid; i < 4096; i += 256) w_s[(i & 63) * 64 + (i >> 6)] = dy_w[i];
    __syncthreads();
    const int oo = (tid >> 5) * 8;
    const int p4 = blockIdx.x * 32 + (tid & 31);
    if (p4 >= 784) return;
    const float* mp = mix + (long)b * CC * HW + p4 * 4;
    float4 acc[8];
    #pragma unroll
    for (int o = 0; o < 8; ++o) acc[o] = make_float4(0.f, 0.f, 0.f, 0.f);
    for (int ii = 0; ii < 64; ii += 8) {
        float4 mv[8];
        #pragma unroll
        for (int u = 0; u < 8; ++u)
            mv[u] = *reinterpret_cast<const float4*>(mp + (long)(ii + u) * HW);
        #pragma unroll
        for (int u = 0; u < 8; ++u) {
            const float* wr = w_s + (ii + u) * 64 + oo;
            #pragma unroll
            for (int o = 0; o < 8; ++o) {
                const float wv = wr[o];
                acc[o].x = fmaf(wv, mv[u].x, acc[o].x);
                acc[o].y = fmaf(wv, mv[u].y, acc[o].y);
                acc[o].z = fmaf(wv, mv[u].z, acc[o].z);
                acc[o].w = fmaf(wv, mv[u].w, acc[o].w);
            }
        }
    }
    float* op = out + (long)b * CC * HW + p4 * 4;
    #pragma unroll
    for (int o = 0; o < 8; ++o) {
        const float sc = s[oo + o], bc = bb[oo + o];
        float4* dst = reinterpret_cast<float4*>(op + (long)(oo + o) * HW);
        float4 prev = *dst;
        prev.x = fmaf(acc[o].x, sc, bc) + prev.x;
        prev.y = fmaf(acc[o].y, sc, bc) + prev.y;
        prev.z = fmaf(acc[o].z, sc, bc) + prev.z;
        prev.w = fmaf(acc[o].w, sc, bc) + prev.w;
        *dst = prev;
    }
}

extern "C" void kernel_launch(void* const* d_in, const int* in_sizes, int n_in,
                              void* d_out, int out_size, void* d_ws, size_t ws_size,
                              hipStream_t stream) {
    const float* x       = (const float*)d_in[0];
    const float* lepe_w  = (const float*)d_in[1];
    const float* lepe_b  = (const float*)d_in[2];
    const float* lepe_s  = (const float*)d_in[3];
    const float* lepe_bb = (const float*)d_in[4];
    const float* wq_w    = (const float*)d_in[5];
    const float* wq_s    = (const float*)d_in[6];
    const float* wq_bb   = (const float*)d_in[7];
    const float* wk_w    = (const float*)d_in[8];
    const float* wk_s    = (const float*)d_in[9];
    const float* wk_bb   = (const float*)d_in[10];
    const float* wp_w    = (const float*)d_in[11];
    const float* wp_b    = (const float*)d_in[12];
    const float* rpb1    = (const float*)d_in[13];
    const float* rpb2    = (const float*)d_in[14];
    const float* dy_w    = (const float*)d_in[15];
    const float* dy_s    = (const float*)d_in[16];
    const float* dy_bb   = (const float*)d_in[17];
    float* out = (float*)d_out;

    float* ws     = (float*)d_ws;
    float* WK_ws  = ws;                               // 128*640            =    81,920 f
    float* q_ws   = WK_ws + 128 * 640;                // 32*32*3136         = 3,211,264 f
    float* mix_ws = q_ws + 32 * 32 * HW;              // 32*64*3136         = 6,422,528 f

    const int nTiles = (HW + 255) / 256;              // 13

    prep_q_k<<<dim3(800 + BB * 4), 256, 0, stream>>>(x, wk_w, wk_s, wk_bb, wp_w,
                                                     wq_w, wq_s, wq_bb, WK_ws, q_ws);
    attnmix_k<<<dim3(nTiles, BB * 4 * 2), 256, 0, stream>>>(x, WK_ws, q_ws,
                                                            wp_b, rpb1, rpb2,
                                                            lepe_w, lepe_b, lepe_s, lepe_bb,
                                                            mix_ws, out);
    final_k<<<dim3(25, BB), 256, 0, stream>>>(mix_ws, dy_w, dy_s, dy_bb, out);
}

// Round 4
// 237.190 us; speedup vs baseline: 1.6736x; 1.6736x over previous
//
#include <hip/hip_runtime.h>

#define BB 32
#define CC 64
#define HH 56
#define WW 56
#define HW 3136
#define TW 64
#define TR 12

// readlane helpers: wave-uniform weight tables cached in VGPRs, fetched with
// compile-time-constant lane indices (legal scalar operand for v_fma).
__device__ __forceinline__ float RL1(float src, int lane) {
    return __int_as_float(__builtin_amdgcn_readlane(__float_as_int(src), lane));
}
#define RLA(arr, idx) RL1(arr[(idx) >> 6], (idx) & 63)

// ---------------- prep: pool(8x8 mean) -> wk matmul+bn -> WK = wp * kg^T ----------------
__global__ __launch_bounds__(256) void prep_k(const float* __restrict__ x,
                                              const float* __restrict__ wk,
                                              const float* __restrict__ wks,
                                              const float* __restrict__ wkb,
                                              const float* __restrict__ wp_w,
                                              float* __restrict__ WK) {
    __shared__ float p_s[32 * 49];
    __shared__ float kg_s[8 * 49];
    const int b = blockIdx.x >> 2;
    const int g = blockIdx.x & 3;
    const int tid = threadIdx.x;
    for (int idx = tid; idx < 1568; idx += 256) {
        const int i = idx / 49, l = idx % 49;
        const int py = l / 7, px = l % 7;
        const float4* xp4 = reinterpret_cast<const float4*>(
            x + ((long)(b * CC + 32 + i)) * HW + py * 8 * WW + px * 8);
        float4 sA = make_float4(0.f, 0.f, 0.f, 0.f);
        float4 sB = make_float4(0.f, 0.f, 0.f, 0.f);
        #pragma unroll
        for (int y = 0; y < 8; ++y) {
            const float4 a = xp4[y * 14];
            const float4 c = xp4[y * 14 + 1];
            sA.x += a.x; sA.y += a.y; sA.z += a.z; sA.w += a.w;
            sB.x += c.x; sB.y += c.y; sB.z += c.z; sB.w += c.w;
        }
        p_s[idx] = (sA.x + sA.y + sA.z + sA.w + sB.x + sB.y + sB.z + sB.w) * (1.f / 64.f);
    }
    __syncthreads();
    for (int idx = tid; idx < 392; idx += 256) {
        const int o8 = idx / 49, l = idx % 49;
        const int o = g * 8 + o8;
        float acc = 0.f;
        #pragma unroll
        for (int i = 0; i < 32; ++i) acc = fmaf(wk[o * 32 + i], p_s[i * 49 + l], acc);
        kg_s[idx] = acc * wks[o] + wkb[o];
    }
    __syncthreads();
    for (int idx = tid; idx < 640; idx += 256) {
        const int c = idx / 80, slot = idx % 80;
        float acc = 0.f;
        int m = -1;
        if (slot < 28) { if (slot < 25) m = slot; }
        else           { if (slot < 77) m = 25 + (slot - 28); }
        if (m >= 0) {
            const float* kp = kg_s + c * 49;
            #pragma unroll
            for (int l = 0; l < 49; ++l) acc = fmaf(wp_w[m * 49 + l], kp[l], acc);
        }
        const long base = (long)blockIdx.x * 640;
        if (slot < 28) WK[base + c * 28 + slot] = acc;
        else           WK[base + 224 + c * 52 + (slot - 28)] = acc;
    }
}

// ---------------- fused q-proj + attention + dyn_mix + lepe ----------------
// Round-0 structure; all wave-uniform weight tables moved from LDS into per-wave
// VGPR caches read via v_readlane (shifts ~1100 instr/thread from the shared
// per-CU LDS pipe to the per-SIMD VALU pipe). LDS = tile + rpb only.
__global__ __launch_bounds__(256) void attnmix_k(const float* __restrict__ x,
                                                 const float* __restrict__ WK,
                                                 const float* __restrict__ wq_w,
                                                 const float* __restrict__ wq_s,
                                                 const float* __restrict__ wq_bb,
                                                 const float* __restrict__ wp_b,
                                                 const float* __restrict__ rpb1,
                                                 const float* __restrict__ rpb2,
                                                 const float* __restrict__ lw,
                                                 const float* __restrict__ lb,
                                                 const float* __restrict__ ls,
                                                 const float* __restrict__ lbb,
                                                 float* __restrict__ mix,
                                                 float* __restrict__ out) {
    __shared__ float tile[8 * TR * TW];   // 24 KB
    __shared__ float rpb1_s[81];
    __shared__ float rpb2_s[169];
    const int tid = threadIdx.x;
    const int lane = tid & 63;
    const int bg = blockIdx.y;
    const int g = bg & 3, b = bg >> 2;

    if (tid < 81) rpb1_s[tid] = rpb1[g * 81 + tid];
    if (tid < 169) rpb2_s[tid] = rpb2[g * 169 + tid];

    // ---- register caches (wave-uniform content) ----
    float wqT_r[4];                        // idx = i*8+c -> wq_w[(g*8+c)*32+i], 256 vals
    #pragma unroll
    for (int r = 0; r < 4; ++r) {
        const int idx = r * 64 + lane, i = idx >> 3, c = idx & 7;
        wqT_r[r] = wq_w[(g * 8 + c) * 32 + i];
    }
    float wqbn_r;                          // lane c = scale[c], lane 8+c = bias[c]
    {
        const int c = lane & 7;
        wqbn_r = (lane < 8) ? wq_s[g * 8 + c] : (lane < 16 ? wq_bb[g * 8 + c] : 0.f);
    }
    float wpb_r[2];                        // wp_b[0..74)
    #pragma unroll
    for (int r = 0; r < 2; ++r) {
        const int idx = r * 64 + lane;
        wpb_r[r] = (idx < 74) ? wp_b[idx] : 0.f;
    }
    const float* wkp = WK + (long)bg * 640;
    float wk1_r[4];                        // 8x28, idx = c*28+m (224 vals)
    #pragma unroll
    for (int r = 0; r < 4; ++r) {
        const int idx = r * 64 + lane;
        wk1_r[r] = (idx < 224) ? wkp[idx] : 0.f;
    }
    float lw1_r[7];                        // lepe w, ch g*8.. (392 vals), idx = ch*49+k
    #pragma unroll
    for (int r = 0; r < 7; ++r) {
        const int idx = r * 64 + lane;
        lw1_r[r] = (idx < 392) ? lw[(g * 8) * 49 + idx] : 0.f;
    }
    float lbn_r;                           // lane = which*16 + c16 (which: 0=b,1=s,2=bb)
    {
        const int which = lane >> 4, c16 = lane & 15;
        const int ch = (c16 < 8) ? (g * 8 + c16) : (32 + g * 8 + (c16 - 8));
        lbn_r = (which == 0) ? lb[ch] : (which == 1) ? ls[ch] : (which == 2) ? lbb[ch] : 0.f;
    }

    const int N0 = blockIdx.x << 8;
    const int ph0 = N0 / WW;               // block-uniform
    const int r0 = ph0 - 3;

    const int n = N0 + tid;
    const bool valid = n < HW;
    const int nc = valid ? n : HW - 1;
    const int ph = nc / WW, pw = nc % WW;
    const int yr = HH - 1 - ph, xr = WW - 1 - pw;
    const int lrow = ph - r0;              // in [3, 8]
    const int tb0 = (lrow - 3) * TW + pw;  // tile offset of tap (0,0)

    const float* xb = x + (long)b * CC * HW + nc;

    // ---- stage v0 tile (channels g*8 .. g*8+8) ----
    {
        const float* xc = x + ((long)b * CC + g * 8) * HW;
        #pragma unroll
        for (int ch = 0; ch < 8; ++ch)
            for (int k = tid; k < TR * TW; k += 256) {
                const int row = k >> 6, lxx = k & 63;
                const int gy = r0 + row, gx = lxx - 3;
                float v = 0.f;
                if ((unsigned)gy < HH && (unsigned)gx < WW) v = xc[ch * HW + gy * WW + gx];
                tile[ch * (TR * TW) + k] = v;
            }
    }

    // ---- q8: q = wq . x[0..32), bn, *SCALE (global reads overlap staging) ----
    float q8[8];
    #pragma unroll
    for (int c = 0; c < 8; ++c) q8[c] = 0.f;
    for (int i = 0; i < 32; ++i) {
        const float xv = xb[i * HW];
        #pragma unroll
        for (int c = 0; c < 8; ++c) q8[c] = fmaf(RLA(wqT_r, i * 8 + c), xv, q8[c]);
    }
    #pragma unroll
    for (int c = 0; c < 8; ++c)
        q8[c] = fmaf(q8[c], RL1(wqbn_r, c), RL1(wqbn_r, 8 + c)) * 0.25f;

    __syncthreads();

    // ======== phase 1: 25-weight softmax, 5x5 gather + lepe 7x7 over v0 ========
    {
        float w1[25];
        #pragma unroll
        for (int m = 0; m < 25; ++m) w1[m] = RLA(wpb_r, m);
        #pragma unroll
        for (int c = 0; c < 8; ++c) {
            const float qv = q8[c];
            #pragma unroll
            for (int m = 0; m < 25; ++m) w1[m] = fmaf(qv, RLA(wk1_r, c * 28 + m), w1[m]);
        }
        const int rh5 = yr < 2 ? yr : (yr > 53 ? yr - 51 : 2);
        const int rw5 = xr < 2 ? xr : (xr > 53 ? xr - 51 : 2);
        #pragma unroll
        for (int i = 0; i < 5; ++i)
            #pragma unroll
            for (int j = 0; j < 5; ++j)
                w1[i * 5 + j] += rpb1_s[(rh5 + i) * 9 + (rw5 + j)];
        float mx = -1e30f;
        #pragma unroll
        for (int m = 0; m < 25; ++m) mx = fmaxf(mx, w1[m]);
        float sm = 0.f;
        #pragma unroll
        for (int m = 0; m < 25; ++m) { w1[m] = __expf(w1[m] - mx); sm += w1[m]; }
        const float r = 1.f / sm;
        #pragma unroll
        for (int m = 0; m < 25; ++m) w1[m] *= r;

        float* m0 = mix + ((long)b * CC + g * 8) * HW + nc;
        float* o0 = out + ((long)b * CC + g * 8) * HW + nc;
        #pragma unroll
        for (int ch = 0; ch < 8; ++ch) {
            const float* t = tile + ch * (TR * TW) + tb0;
            float a = 0.f, la = 0.f;
            #pragma unroll
            for (int i = 0; i < 7; ++i)
                #pragma unroll
                for (int j = 0; j < 7; ++j) {
                    const float v = t[i * TW + j];
                    la = fmaf(RLA(lw1_r, ch * 49 + i * 7 + j), v, la);
                    if (i >= 1 && i <= 5 && j >= 1 && j <= 5)
                        a = fmaf(w1[(i - 1) * 5 + (j - 1)], v, a);
                }
            if (valid) {
                m0[ch * HW] = a;
                o0[ch * HW] = (la + RL1(lbn_r, ch)) * RL1(lbn_r, 16 + ch) + RL1(lbn_r, 32 + ch);
            }
        }
    }

    // ---- load phase-2 caches (latency hides under barrier + re-stage) ----
    float wk2_r[7];                        // 8x52, idx = c*52+m (416 vals)
    #pragma unroll
    for (int r = 0; r < 7; ++r) {
        const int idx = r * 64 + lane;
        wk2_r[r] = (idx < 416) ? wkp[224 + idx] : 0.f;
    }
    float lw2_r[7];                        // lepe w, ch 32+g*8.. (392 vals)
    #pragma unroll
    for (int r = 0; r < 7; ++r) {
        const int idx = r * 64 + lane;
        lw2_r[r] = (idx < 392) ? lw[(32 + g * 8) * 49 + idx] : 0.f;
    }

    __syncthreads();                       // tile reads done
    // ---- re-stage tile with v1 channels (32 + g*8 ..) ----
    {
        const float* xc = x + ((long)b * CC + 32 + g * 8) * HW;
        #pragma unroll
        for (int ch = 0; ch < 8; ++ch)
            for (int k = tid; k < TR * TW; k += 256) {
                const int row = k >> 6, lxx = k & 63;
                const int gy = r0 + row, gx = lxx - 3;
                float v = 0.f;
                if ((unsigned)gy < HH && (unsigned)gx < WW) v = xc[ch * HW + gy * WW + gx];
                tile[ch * (TR * TW) + k] = v;
            }
    }
    __syncthreads();

    // ======== phase 2: 49-weight softmax, 7x7 gather + lepe 7x7 over v1 ========
    {
        float w2[49];
        #pragma unroll
        for (int m = 0; m < 49; ++m) w2[m] = RLA(wpb_r, 25 + m);
        #pragma unroll
        for (int c = 0; c < 8; ++c) {
            const float qv = q8[c];
            #pragma unroll
            for (int m = 0; m < 49; ++m) w2[m] = fmaf(qv, RLA(wk2_r, c * 52 + m), w2[m]);
        }
        const int rh7 = yr < 3 ? yr : (yr > 52 ? yr - 49 : 3);
        const int rw7 = xr < 3 ? xr : (xr > 52 ? xr - 49 : 3);
        #pragma unroll
        for (int i = 0; i < 7; ++i)
            #pragma unroll
            for (int j = 0; j < 7; ++j)
                w2[i * 7 + j] += rpb2_s[(rh7 + i) * 13 + (rw7 + j)];
        float mx = -1e30f;
        #pragma unroll
        for (int m = 0; m < 49; ++m) mx = fmaxf(mx, w2[m]);
        float sm = 0.f;
        #pragma unroll
        for (int m = 0; m < 49; ++m) { w2[m] = __expf(w2[m] - mx); sm += w2[m]; }
        const float r = 1.f / sm;
        #pragma unroll
        for (int m = 0; m < 49; ++m) w2[m] *= r;

        float* m1 = mix + ((long)b * CC + 32 + g * 8) * HW + nc;
        float* o1 = out + ((long)b * CC + 32 + g * 8) * HW + nc;
        #pragma unroll
        for (int ch = 0; ch < 8; ++ch) {
            const float* t = tile + ch * (TR * TW) + tb0;
            float a = 0.f, la = 0.f;
            #pragma unroll
            for (int i = 0; i < 7; ++i)
                #pragma unroll
                for (int j = 0; j < 7; ++j) {
                    const float v = t[i * TW + j];
                    la = fmaf(RLA(lw2_r, ch * 49 + i * 7 + j), v, la);
                    a  = fmaf(w2[i * 7 + j], v, a);
                }
            if (valid) {
                m1[ch * HW] = a;
                o1[ch * HW] = (la + RL1(lbn_r, 8 + ch)) * RL1(lbn_r, 24 + ch) + RL1(lbn_r, 40 + ch);
            }
        }
    }
}

// ---------------- final: 64x64 channel matmul + bn + lepe add ----------------
__global__ __launch_bounds__(256) void final_k(const float* __restrict__ mix,
                                               const float* __restrict__ dy_w,
                                               const float* __restrict__ s,
                                               const float* __restrict__ bb,
                                               float* __restrict__ out) {
    __shared__ float w_s[64 * 64];      // transposed: w_s[i*64+o] = dy_w[o*64+i]
    const int tid = threadIdx.x;
    const int b = blockIdx.y;
    for (int i = tid; i < 4096; i += 256) w_s[(i & 63) * 64 + (i >> 6)] = dy_w[i];
    __syncthreads();
    const int oo = (tid >> 5) * 8;                  // output octant base
    const int p4 = blockIdx.x * 32 + (tid & 31);    // float4 pixel group, need < 784
    if (p4 >= 784) return;
    const float* mp = mix + (long)b * CC * HW + p4 * 4;
    float4 acc[8];
    #pragma unroll
    for (int o = 0; o < 8; ++o) acc[o] = make_float4(0.f, 0.f, 0.f, 0.f);
    for (int ii = 0; ii < 64; ii += 8) {
        float4 mv[8];
        #pragma unroll
        for (int u = 0; u < 8; ++u)
            mv[u] = *reinterpret_cast<const float4*>(mp + (long)(ii + u) * HW);
        #pragma unroll
        for (int u = 0; u < 8; ++u) {
            const float* wr = w_s + (ii + u) * 64 + oo;
            #pragma unroll
            for (int o = 0; o < 8; ++o) {
                const float wv = wr[o];
                acc[o].x = fmaf(wv, mv[u].x, acc[o].x);
                acc[o].y = fmaf(wv, mv[u].y, acc[o].y);
                acc[o].z = fmaf(wv, mv[u].z, acc[o].z);
                acc[o].w = fmaf(wv, mv[u].w, acc[o].w);
            }
        }
    }
    float* op = out + (long)b * CC * HW + p4 * 4;
    #pragma unroll
    for (int o = 0; o < 8; ++o) {
        const float sc = s[oo + o], bc = bb[oo + o];
        float4* dst = reinterpret_cast<float4*>(op + (long)(oo + o) * HW);
        float4 prev = *dst;
        prev.x = fmaf(acc[o].x, sc, bc) + prev.x;
        prev.y = fmaf(acc[o].y, sc, bc) + prev.y;
        prev.z = fmaf(acc[o].z, sc, bc) + prev.z;
        prev.w = fmaf(acc[o].w, sc, bc) + prev.w;
        *dst = prev;
    }
}

extern "C" void kernel_launch(void* const* d_in, const int* in_sizes, int n_in,
                              void* d_out, int out_size, void* d_ws, size_t ws_size,
                              hipStream_t stream) {
    const float* x       = (const float*)d_in[0];
    const float* lepe_w  = (const float*)d_in[1];
    const float* lepe_b  = (const float*)d_in[2];
    const float* lepe_s  = (const float*)d_in[3];
    const float* lepe_bb = (const float*)d_in[4];
    const float* wq_w    = (const float*)d_in[5];
    const float* wq_s    = (const float*)d_in[6];
    const float* wq_bb   = (const float*)d_in[7];
    const float* wk_w    = (const float*)d_in[8];
    const float* wk_s    = (const float*)d_in[9];
    const float* wk_bb   = (const float*)d_in[10];
    const float* wp_w    = (const float*)d_in[11];
    const float* wp_b    = (const float*)d_in[12];
    const float* rpb1    = (const float*)d_in[13];
    const float* rpb2    = (const float*)d_in[14];
    const float* dy_w    = (const float*)d_in[15];
    const float* dy_s    = (const float*)d_in[16];
    const float* dy_bb   = (const float*)d_in[17];
    float* out = (float*)d_out;

    float* ws     = (float*)d_ws;
    float* WK_ws  = ws;                               // 128*640 = 81920
    float* mix_ws = WK_ws + 128 * 640;                // 32*64*3136 = 6422528

    const int nTiles = (HW + 255) / 256;              // 13

    prep_k<<<dim3(BB * 4), 256, 0, stream>>>(x, wk_w, wk_s, wk_bb, wp_w, WK_ws);
    attnmix_k<<<dim3(nTiles, BB * 4), 256, 0, stream>>>(x, WK_ws, wq_w, wq_s, wq_bb,
                                                        wp_b, rpb1, rpb2,
                                                        lepe_w, lepe_b, lepe_s, lepe_bb,
                                                        mix_ws, out);
    final_k<<<dim3(25, BB), 256, 0, stream>>>(mix_ws, dy_w, dy_s, dy_bb, out);
}